// Round 10
// baseline (2307.232 us; speedup 1.0000x reference)
//
#include <hip/hip_runtime.h>

// TruncatedHistoryAttn, round 16: FUSED single kernel.
// Round-15 post-mortem: phase2=857us but total=1131 -> ~275us is phase1 +
// memset + launches. Phase2 consumes A=H@W1 and B2=H@W2 ONLY at the WG's own
// 64 cols (ring values, waves 0-4) -> each is a 512-k col-slice matvec of the
// exact same shape as the existing W3 matvec. So phase1 is eliminated:
//  - W1/W2/W3 col-slices all in VGPRs (3 x 64 = 192 regs, <=256 -> 2 w/SIMD).
//  - Per step THREE interleaved matvecs: c_t = tilde_t@W3, a_t = H_t@W1,
//    b_{t+2} = H_{t+2}@W2 (48 ds_read_b128 + 192 fma), partials in pm0/1/2,
//    one barrier C, waves 0-4 reduce all three (24 wave-uniform LDS reads).
//  - H rows staged like tlds: write hA[tid]=h_cur, hB[tid]=h_n2, then
//    lgkmcnt(0); matvec reads are wave-local (wave q reads [q*64,q*64+64)) ->
//    no extra barrier.
//  - b computed at step t IS btB for step t+1 (B2 row t+2) - same 2-step
//    pipeline the old global prefetch had. Prologue computes btB = B2 row 1.
//  - A/B2 never materialized: -64MB workspace traffic, -1 launch, d_out is
//    written only with tilde rows (row t at step t, g==0) -> full overwrite.
// Kept from round 15: tagged 8B agent words, early distributed publish
// (waves 1..4 at step start, j=4 at tail), wave-0-only poll with self-j4
// register substitute, DPP cross-lane sums, 2 barriers/step, grid 256.

#define BB 32
#define SS 512
#define DD 512
#define NS 5

#define EXCH_U64_PER_B 128                           // 2 slots x 64 (40 used)
#define EXCH_BYTES ((size_t)BB * EXCH_U64_PER_B * 8) // 32 KB
#define WS_NEED    EXCH_BYTES

typedef __attribute__((ext_vector_type(4))) float f32x4;

// ---- DPP cross-lane sum (rocPRIM sequence); ctrl words are template consts.
template <int CTRL, int RMASK, int BMASK, bool BC>
__device__ __forceinline__ float dpp_term(float x) {
  return __uint_as_float((unsigned)__builtin_amdgcn_update_dpp(
      0, (int)__float_as_uint(x), CTRL, RMASK, BMASK, BC));
}
__device__ __forceinline__ float wave_sum64(float x) {
  x += dpp_term<0xB1, 0xF, 0xF, true>(x);   // quad_perm [1,0,3,2] (xor 1)
  x += dpp_term<0x4E, 0xF, 0xF, true>(x);   // quad_perm [2,3,0,1] (xor 2)
  x += dpp_term<0x141, 0xF, 0xF, true>(x);  // row_half_mirror     (xor 4)
  x += dpp_term<0x140, 0xF, 0xF, true>(x);  // row_mirror          (xor 8)
  x += dpp_term<0x142, 0xA, 0xF, false>(x); // row_bcast15 -> rows 1,3
  x += dpp_term<0x143, 0xC, 0xF, false>(x); // row_bcast31 -> rows 2,3
  return x;                                 // lane 63: sum of all 64
}
__device__ __forceinline__ float group8_sum(float x) {
  x += dpp_term<0xB1, 0xF, 0xF, true>(x);
  x += dpp_term<0x4E, 0xF, 0xF, true>(x);
  x += dpp_term<0x141, 0xF, 0xF, true>(x);
  return x;
}

// grid 256 = 8 WGs/batch; bid = g*32+b.
__global__ void __launch_bounds__(512) th_fused(
    const float* __restrict__ H, const float* __restrict__ v,
    const float* __restrict__ W1, const float* __restrict__ W2,
    const float* __restrict__ W3,
    float* __restrict__ Ob,            // d_out: tilde rows only
    unsigned long long* __restrict__ exch) {
  const int tid = threadIdx.x;
  const int b = blockIdx.x & 31;
  const int g = blockIdx.x >> 5;     // 0..7: cols [g*64, g*64+64)
  const int q = tid >> 6;            // wave id == k-segment 0..7
  const int ln = tid & 63;
  const int col = (g << 6) + ln;

  __shared__ float tlds[DD];         // tilde_t row
  __shared__ float hA[DD];           // H row t
  __shared__ float hB[DD];           // H row t+2
  __shared__ float pm0[DD];          // W3-matvec partials (c)
  __shared__ float pm1[DD];          // W1-matvec partials (a)
  __shared__ float pm2[DD];          // W2-matvec partials (b)
  __shared__ float wl[8];            // softmax weights broadcast

  // weight col-slices in VGPRs: w?[i] = W?[q*64+i][col]
  float wa3[64], wa1[64], wa2[64];
#pragma unroll
  for (int i = 0; i < 64; ++i) {
    const size_t off = (size_t)(q * 64 + i) * DD + col;
    wa3[i] = W3[off];
    wa1[i] = W1[off];
    wa2[i] = W2[off];
  }

  const float* Hb = H + (size_t)b * SS * DD;
  float* Op = Ob + (size_t)b * SS * DD;
  unsigned long long* eb = exch + (size_t)b * EXCH_U64_PER_B;

  // waves 0..4: replica rings over this WG's 64 cols (row s in slot s%5)
  float v_col = (q < NS) ? v[col] : 0.f;
  float aA[NS] = {0.f, 0.f, 0.f, 0.f, 0.f};
  float cC[NS] = {0.f, 0.f, 0.f, 0.f, 0.f};
  float tl[NS] = {0.f, 0.f, 0.f, 0.f, 0.f};
  float s4_prev = 0.f;               // wave 0: own j=4 score (all lanes)
  float h_cur = Hb[tid];             // H row 0
  float h_n1  = Hb[DD + tid];        // H row 1
  float btB = 0.f;                   // B2 row t+1 at own col (waves 0-4)

  if (tid < NS) wl[tid] = 0.2f;      // step-0 weights: exactly uniform

  // ---- prologue: btB = B2 row 1 = H_1 @ W2 (col-slice matvec)
  {
    hB[tid] = h_n1;
    asm volatile("s_waitcnt lgkmcnt(0)" ::: "memory");
    float a0 = 0.f, a1 = 0.f, a2 = 0.f, a3 = 0.f;
    const f32x4* tv = (const f32x4*)&hB[q << 6];
#pragma unroll
    for (int i = 0; i < 16; ++i) {
      f32x4 t4 = tv[i];
      a0 = fmaf(t4.x, wa2[4 * i + 0], a0);
      a1 = fmaf(t4.y, wa2[4 * i + 1], a1);
      a2 = fmaf(t4.z, wa2[4 * i + 2], a2);
      a3 = fmaf(t4.w, wa2[4 * i + 3], a3);
    }
    pm2[tid] = (a0 + a1) + (a2 + a3);
    __syncthreads();
    if (q < NS) {
      float bb = 0.f;
#pragma unroll
      for (int s = 0; s < 8; ++s) bb += pm2[s * 64 + ln];
      btB = bb;
    }
    __syncthreads();                 // pm2 free for step-0 reuse
  }

#pragma unroll 1
  for (int t5 = 0; t5 < 515; t5 += 5) {
#pragma unroll
    for (int p = 0; p < NS; ++p) {
      const int t = t5 + p;
      if (t < SS) {
        const bool pub = (t + 1 < SS);

        // ---- prefetch H row t+2 (staged into hB this step, b-matvec)
        float h_n2 = 0.f;
        if (t + 2 < SS) h_n2 = Hb[(size_t)(t + 2) * DD + tid];

        // ---- waves 1..4: EARLY publish of score j=q-1 for step t+1
        if (q >= 1 && q < NS && pub) {
          float aa = aA[(p + 1) % NS];
          aa = (q == 2) ? aA[(p + 2) % NS] : aa;
          aa = (q == 3) ? aA[(p + 3) % NS] : aa;
          aa = (q == 4) ? aA[(p + 4) % NS] : aa;
          float cc = cC[(p + 1) % NS];
          cc = (q == 2) ? cC[(p + 2) % NS] : cc;
          cc = (q == 3) ? cC[(p + 3) % NS] : cc;
          cc = (q == 4) ? cC[(p + 4) % NS] : cc;
          float x = aa + btB + cc;
          float e = __expf(2.0f * x);
          float s = (1.0f - 2.0f / (e + 1.0f)) * v_col;
          s = wave_sum64(s);                       // lane 63 = total
          if (ln == 63)
            __hip_atomic_store(&eb[(size_t)((t + 1) & 1) * 64 + (q - 1) * 8 + g],
                (unsigned long long)__float_as_uint(s) |
                    ((unsigned long long)(t + 2) << 32),
                __ATOMIC_RELAXED, __HIP_MEMORY_SCOPE_AGENT);
        }

        // ---- wave 0: poll tagged words (slot t&1, tag t+1) -> softmax -> wl
        if (q == 0 && t >= 1) {
          const unsigned long long* wsl = eb + (size_t)(t & 1) * 64;
          float pv = 0.f;
          if (ln < 40) {
            if (!((ln >> 3) == 4 && (ln & 7) == g)) {
              unsigned long long w;
              do {
                w = __hip_atomic_load(&wsl[ln], __ATOMIC_RELAXED,
                                      __HIP_MEMORY_SCOPE_AGENT);
              } while ((unsigned)(w >> 32) != (unsigned)(t + 1));
              pv = __uint_as_float((unsigned)w);
            } else {
              pv = s4_prev;
            }
          }
          pv = group8_sum(pv);             // each 8-group holds its j-total
          float sc0 = __shfl(pv, 0, 64);
          float sc1 = __shfl(pv, 8, 64);
          float sc2 = __shfl(pv, 16, 64);
          float sc3 = __shfl(pv, 24, 64);
          float sc4 = __shfl(pv, 32, 64);
          float mx = fmaxf(fmaxf(fmaxf(sc0, sc1), fmaxf(sc2, sc3)), sc4);
          float e0 = __expf(sc0 - mx), e1 = __expf(sc1 - mx);
          float e2 = __expf(sc2 - mx), e3 = __expf(sc3 - mx);
          float e4 = __expf(sc4 - mx);
          float inv = 1.0f / (e0 + e1 + e2 + e3 + e4);
          float wv = e0 * inv;
          wv = (ln == 1) ? e1 * inv : wv;
          wv = (ln == 2) ? e2 * inv : wv;
          wv = (ln == 3) ? e3 * inv : wv;
          wv = (ln == 4) ? e4 * inv : wv;
          if (ln < NS) wl[ln] = wv;
        }
        __syncthreads();                           // A: weights ready

        // ---- all threads: tilde row; stage tilde + H_t + H_{t+2} into LDS
        float w0 = wl[0], w1 = wl[1], w2 = wl[2], w3_ = wl[3], w4 = wl[4];
        float hh = w0 * tl[p];
        hh = fmaf(w1, tl[(p + 1) % NS], hh);
        hh = fmaf(w2, tl[(p + 2) % NS], hh);
        hh = fmaf(w3_, tl[(p + 3) % NS], hh);
        hh = fmaf(w4, tl[(p + 4) % NS], hh);
        float tld = h_cur + fmaxf(hh, 0.f);
        tl[p] = tld;
        tlds[tid] = tld;
        hA[tid] = h_cur;
        hB[tid] = h_n2;
        if (g == 0) Op[(size_t)t * DD + tid] = tld;  // output row t
        // wave-local: matvecs read ONLY this wave's own LDS segments
        asm volatile("s_waitcnt lgkmcnt(0)" ::: "memory");

        // ---- 3 interleaved matvecs: c_t (W3), a_t (W1), b_{t+2} (W2)
        float c0 = 0.f, c1 = 0.f, c2 = 0.f, c3 = 0.f;
        float d0 = 0.f, d1 = 0.f, d2 = 0.f, d3 = 0.f;
        float f0 = 0.f, f1 = 0.f, f2 = 0.f, f3 = 0.f;
        const f32x4* tvT = (const f32x4*)&tlds[q << 6];
        const f32x4* tvA = (const f32x4*)&hA[q << 6];
        const f32x4* tvB = (const f32x4*)&hB[q << 6];
#pragma unroll
        for (int i = 0; i < 16; ++i) {
          f32x4 tt = tvT[i];
          f32x4 ta = tvA[i];
          f32x4 tb = tvB[i];
          c0 = fmaf(tt.x, wa3[4 * i + 0], c0);
          c1 = fmaf(tt.y, wa3[4 * i + 1], c1);
          c2 = fmaf(tt.z, wa3[4 * i + 2], c2);
          c3 = fmaf(tt.w, wa3[4 * i + 3], c3);
          d0 = fmaf(ta.x, wa1[4 * i + 0], d0);
          d1 = fmaf(ta.y, wa1[4 * i + 1], d1);
          d2 = fmaf(ta.z, wa1[4 * i + 2], d2);
          d3 = fmaf(ta.w, wa1[4 * i + 3], d3);
          f0 = fmaf(tb.x, wa2[4 * i + 0], f0);
          f1 = fmaf(tb.y, wa2[4 * i + 1], f1);
          f2 = fmaf(tb.z, wa2[4 * i + 2], f2);
          f3 = fmaf(tb.w, wa2[4 * i + 3], f3);
        }
        pm0[tid] = (c0 + c1) + (c2 + c3);
        pm1[tid] = (d0 + d1) + (d2 + d3);
        pm2[tid] = (f0 + f1) + (f2 + f3);
        __syncthreads();                           // C: pm ready

        // ---- waves 0..4: reduce c_t, a_t, b_{t+2}; wave 0: j=4 publish
        if (q < NS) {
          float c = 0.f, a = 0.f, bb = 0.f;
#pragma unroll
          for (int s = 0; s < 8; ++s) {
            c  += pm0[s * 64 + ln];
            a  += pm1[s * 64 + ln];
            bb += pm2[s * 64 + ln];
          }
          aA[p] = a;                               // A row t -> slot t%5
          cC[p] = c;                               // c row t -> slot t%5
          if (q == 0 && pub) {
            float x = a + btB + c;                 // row t, bt = row t+1
            float e = __expf(2.0f * x);
            float s4 = (1.0f - 2.0f / (e + 1.0f)) * v_col;
            s4 = wave_sum64(s4);                   // lane 63 = total
            if (ln == 63)
              __hip_atomic_store(&eb[(size_t)((t + 1) & 1) * 64 + 32 + g],
                  (unsigned long long)__float_as_uint(s4) |
                      ((unsigned long long)(t + 2) << 32),
                  __ATOMIC_RELAXED, __HIP_MEMORY_SCOPE_AGENT);
            s4_prev = __shfl(s4, 63, 64);          // off-critical broadcast
          }
          btB = bb;                                // B2 row t+2 for step t+1
        }
        h_cur = h_n1;
        h_n1 = h_n2;
      }
    }
  }
}

extern "C" void kernel_launch(void* const* d_in, const int* in_sizes, int n_in,
                              void* d_out, int out_size, void* d_ws, size_t ws_size,
                              hipStream_t stream) {
  const float* H  = (const float*)d_in[0];
  const float* v  = (const float*)d_in[1];
  const float* W1 = (const float*)d_in[2];
  const float* W2 = (const float*)d_in[3];
  const float* W3 = (const float*)d_in[4];
  float* out = (float*)d_out;

  if (ws_size < WS_NEED) return;

  unsigned long long* exch = (unsigned long long*)d_ws;

  (void)hipMemsetAsync(exch, 0, EXCH_BYTES, stream);
  hipLaunchKernelGGL(th_fused, dim3(BB * 8), dim3(512), 0, stream,
                     H, v, W1, W2, W3, out, exch);
}

// Round 11
// 2290.061 us; speedup vs baseline: 1.0075x; 1.0075x over previous
//
#include <hip/hip_runtime.h>

// TruncatedHistoryAttn, round 17 = round 16 (fused) + __launch_bounds__(512,1).
// Round-16 post-mortem: fusion was correct but the compiler's default
// occupancy target capped VGPRs at 128 -> the 192-float weight arrays spilled
// to scratch (WRITE 53->77MB, 2.4ms). With a 512-thread block the HW floor is
// 2 waves/SIMD, so (512,1) legalizes up to 256 VGPRs -> spill-free.
// Round-15 counters show phase2 already runs 1 WG/CU (occupancy 22.6% = 8
// waves/CU), so there is no co-residency lost by the fat-register design.
// Design (unchanged from round 16):
//  - Single kernel; phase1 eliminated. W1/W2/W3 col-slices in VGPRs (192).
//  - Per step THREE interleaved wave-local matvecs: c_t = tilde_t@W3,
//    a_t = H_t@W1, b_{t+2} = H_{t+2}@W2; partials pm0/1/2; one barrier C;
//    waves 0-4 reduce all three (24 wave-uniform LDS reads).
//  - H rows staged like tlds (write + lgkmcnt(0), wave-local reads).
//  - b computed at step t IS btB for step t+1; prologue computes B2 row 1.
//  - A/B2 never materialized: -64MB workspace traffic, -1 launch; d_out gets
//    only tilde rows (row t at step t, g==0) -> full overwrite.
// Kept from round 15: tagged 8B agent words, early distributed publish
// (waves 1..4 at step start, j=4 at tail), wave-0-only poll with self-j4
// register substitute, DPP cross-lane sums, 2 barriers/step, grid 256.

#define BB 32
#define SS 512
#define DD 512
#define NS 5

#define EXCH_U64_PER_B 128                           // 2 slots x 64 (40 used)
#define EXCH_BYTES ((size_t)BB * EXCH_U64_PER_B * 8) // 32 KB
#define WS_NEED    EXCH_BYTES

typedef __attribute__((ext_vector_type(4))) float f32x4;

// ---- DPP cross-lane sum (rocPRIM sequence); ctrl words are template consts.
template <int CTRL, int RMASK, int BMASK, bool BC>
__device__ __forceinline__ float dpp_term(float x) {
  return __uint_as_float((unsigned)__builtin_amdgcn_update_dpp(
      0, (int)__float_as_uint(x), CTRL, RMASK, BMASK, BC));
}
__device__ __forceinline__ float wave_sum64(float x) {
  x += dpp_term<0xB1, 0xF, 0xF, true>(x);   // quad_perm [1,0,3,2] (xor 1)
  x += dpp_term<0x4E, 0xF, 0xF, true>(x);   // quad_perm [2,3,0,1] (xor 2)
  x += dpp_term<0x141, 0xF, 0xF, true>(x);  // row_half_mirror     (xor 4)
  x += dpp_term<0x140, 0xF, 0xF, true>(x);  // row_mirror          (xor 8)
  x += dpp_term<0x142, 0xA, 0xF, false>(x); // row_bcast15 -> rows 1,3
  x += dpp_term<0x143, 0xC, 0xF, false>(x); // row_bcast31 -> rows 2,3
  return x;                                 // lane 63: sum of all 64
}
__device__ __forceinline__ float group8_sum(float x) {
  x += dpp_term<0xB1, 0xF, 0xF, true>(x);
  x += dpp_term<0x4E, 0xF, 0xF, true>(x);
  x += dpp_term<0x141, 0xF, 0xF, true>(x);
  return x;
}

// grid 256 = 8 WGs/batch; bid = g*32+b.
__global__ void __launch_bounds__(512, 1) th_fused(
    const float* __restrict__ H, const float* __restrict__ v,
    const float* __restrict__ W1, const float* __restrict__ W2,
    const float* __restrict__ W3,
    float* __restrict__ Ob,            // d_out: tilde rows only
    unsigned long long* __restrict__ exch) {
  const int tid = threadIdx.x;
  const int b = blockIdx.x & 31;
  const int g = blockIdx.x >> 5;     // 0..7: cols [g*64, g*64+64)
  const int q = tid >> 6;            // wave id == k-segment 0..7
  const int ln = tid & 63;
  const int col = (g << 6) + ln;

  __shared__ float tlds[DD];         // tilde_t row
  __shared__ float hA[DD];           // H row t
  __shared__ float hB[DD];           // H row t+2
  __shared__ float pm0[DD];          // W3-matvec partials (c)
  __shared__ float pm1[DD];          // W1-matvec partials (a)
  __shared__ float pm2[DD];          // W2-matvec partials (b)
  __shared__ float wl[8];            // softmax weights broadcast

  // weight col-slices in VGPRs: w?[i] = W?[q*64+i][col]
  float wa3[64], wa1[64], wa2[64];
#pragma unroll
  for (int i = 0; i < 64; ++i) {
    const size_t off = (size_t)(q * 64 + i) * DD + col;
    wa3[i] = W3[off];
    wa1[i] = W1[off];
    wa2[i] = W2[off];
  }

  const float* Hb = H + (size_t)b * SS * DD;
  float* Op = Ob + (size_t)b * SS * DD;
  unsigned long long* eb = exch + (size_t)b * EXCH_U64_PER_B;

  // waves 0..4: replica rings over this WG's 64 cols (row s in slot s%5)
  float v_col = (q < NS) ? v[col] : 0.f;
  float aA[NS] = {0.f, 0.f, 0.f, 0.f, 0.f};
  float cC[NS] = {0.f, 0.f, 0.f, 0.f, 0.f};
  float tl[NS] = {0.f, 0.f, 0.f, 0.f, 0.f};
  float s4_prev = 0.f;               // wave 0: own j=4 score (all lanes)
  float h_cur = Hb[tid];             // H row 0
  float h_n1  = Hb[DD + tid];        // H row 1
  float btB = 0.f;                   // B2 row t+1 at own col (waves 0-4)

  if (tid < NS) wl[tid] = 0.2f;      // step-0 weights: exactly uniform

  // ---- prologue: btB = B2 row 1 = H_1 @ W2 (col-slice matvec)
  {
    hB[tid] = h_n1;
    asm volatile("s_waitcnt lgkmcnt(0)" ::: "memory");
    float a0 = 0.f, a1 = 0.f, a2 = 0.f, a3 = 0.f;
    const f32x4* tv = (const f32x4*)&hB[q << 6];
#pragma unroll
    for (int i = 0; i < 16; ++i) {
      f32x4 t4 = tv[i];
      a0 = fmaf(t4.x, wa2[4 * i + 0], a0);
      a1 = fmaf(t4.y, wa2[4 * i + 1], a1);
      a2 = fmaf(t4.z, wa2[4 * i + 2], a2);
      a3 = fmaf(t4.w, wa2[4 * i + 3], a3);
    }
    pm2[tid] = (a0 + a1) + (a2 + a3);
    __syncthreads();
    if (q < NS) {
      float bb = 0.f;
#pragma unroll
      for (int s = 0; s < 8; ++s) bb += pm2[s * 64 + ln];
      btB = bb;
    }
    __syncthreads();                 // pm2 free for step-0 reuse
  }

#pragma unroll 1
  for (int t5 = 0; t5 < 515; t5 += 5) {
#pragma unroll
    for (int p = 0; p < NS; ++p) {
      const int t = t5 + p;
      if (t < SS) {
        const bool pub = (t + 1 < SS);

        // ---- prefetch H row t+2 (staged into hB this step, b-matvec)
        float h_n2 = 0.f;
        if (t + 2 < SS) h_n2 = Hb[(size_t)(t + 2) * DD + tid];

        // ---- waves 1..4: EARLY publish of score j=q-1 for step t+1
        if (q >= 1 && q < NS && pub) {
          float aa = aA[(p + 1) % NS];
          aa = (q == 2) ? aA[(p + 2) % NS] : aa;
          aa = (q == 3) ? aA[(p + 3) % NS] : aa;
          aa = (q == 4) ? aA[(p + 4) % NS] : aa;
          float cc = cC[(p + 1) % NS];
          cc = (q == 2) ? cC[(p + 2) % NS] : cc;
          cc = (q == 3) ? cC[(p + 3) % NS] : cc;
          cc = (q == 4) ? cC[(p + 4) % NS] : cc;
          float x = aa + btB + cc;
          float e = __expf(2.0f * x);
          float s = (1.0f - 2.0f / (e + 1.0f)) * v_col;
          s = wave_sum64(s);                       // lane 63 = total
          if (ln == 63)
            __hip_atomic_store(&eb[(size_t)((t + 1) & 1) * 64 + (q - 1) * 8 + g],
                (unsigned long long)__float_as_uint(s) |
                    ((unsigned long long)(t + 2) << 32),
                __ATOMIC_RELAXED, __HIP_MEMORY_SCOPE_AGENT);
        }

        // ---- wave 0: poll tagged words (slot t&1, tag t+1) -> softmax -> wl
        if (q == 0 && t >= 1) {
          const unsigned long long* wsl = eb + (size_t)(t & 1) * 64;
          float pv = 0.f;
          if (ln < 40) {
            if (!((ln >> 3) == 4 && (ln & 7) == g)) {
              unsigned long long w;
              do {
                w = __hip_atomic_load(&wsl[ln], __ATOMIC_RELAXED,
                                      __HIP_MEMORY_SCOPE_AGENT);
              } while ((unsigned)(w >> 32) != (unsigned)(t + 1));
              pv = __uint_as_float((unsigned)w);
            } else {
              pv = s4_prev;
            }
          }
          pv = group8_sum(pv);             // each 8-group holds its j-total
          float sc0 = __shfl(pv, 0, 64);
          float sc1 = __shfl(pv, 8, 64);
          float sc2 = __shfl(pv, 16, 64);
          float sc3 = __shfl(pv, 24, 64);
          float sc4 = __shfl(pv, 32, 64);
          float mx = fmaxf(fmaxf(fmaxf(sc0, sc1), fmaxf(sc2, sc3)), sc4);
          float e0 = __expf(sc0 - mx), e1 = __expf(sc1 - mx);
          float e2 = __expf(sc2 - mx), e3 = __expf(sc3 - mx);
          float e4 = __expf(sc4 - mx);
          float inv = 1.0f / (e0 + e1 + e2 + e3 + e4);
          float wv = e0 * inv;
          wv = (ln == 1) ? e1 * inv : wv;
          wv = (ln == 2) ? e2 * inv : wv;
          wv = (ln == 3) ? e3 * inv : wv;
          wv = (ln == 4) ? e4 * inv : wv;
          if (ln < NS) wl[ln] = wv;
        }
        __syncthreads();                           // A: weights ready

        // ---- all threads: tilde row; stage tilde + H_t + H_{t+2} into LDS
        float w0 = wl[0], w1 = wl[1], w2 = wl[2], w3_ = wl[3], w4 = wl[4];
        float hh = w0 * tl[p];
        hh = fmaf(w1, tl[(p + 1) % NS], hh);
        hh = fmaf(w2, tl[(p + 2) % NS], hh);
        hh = fmaf(w3_, tl[(p + 3) % NS], hh);
        hh = fmaf(w4, tl[(p + 4) % NS], hh);
        float tld = h_cur + fmaxf(hh, 0.f);
        tl[p] = tld;
        tlds[tid] = tld;
        hA[tid] = h_cur;
        hB[tid] = h_n2;
        if (g == 0) Op[(size_t)t * DD + tid] = tld;  // output row t
        // wave-local: matvecs read ONLY this wave's own LDS segments
        asm volatile("s_waitcnt lgkmcnt(0)" ::: "memory");

        // ---- 3 interleaved matvecs: c_t (W3), a_t (W1), b_{t+2} (W2)
        float c0 = 0.f, c1 = 0.f, c2 = 0.f, c3 = 0.f;
        float d0 = 0.f, d1 = 0.f, d2 = 0.f, d3 = 0.f;
        float f0 = 0.f, f1 = 0.f, f2 = 0.f, f3 = 0.f;
        const f32x4* tvT = (const f32x4*)&tlds[q << 6];
        const f32x4* tvA = (const f32x4*)&hA[q << 6];
        const f32x4* tvB = (const f32x4*)&hB[q << 6];
#pragma unroll
        for (int i = 0; i < 16; ++i) {
          f32x4 tt = tvT[i];
          f32x4 ta = tvA[i];
          f32x4 tb = tvB[i];
          c0 = fmaf(tt.x, wa3[4 * i + 0], c0);
          c1 = fmaf(tt.y, wa3[4 * i + 1], c1);
          c2 = fmaf(tt.z, wa3[4 * i + 2], c2);
          c3 = fmaf(tt.w, wa3[4 * i + 3], c3);
          d0 = fmaf(ta.x, wa1[4 * i + 0], d0);
          d1 = fmaf(ta.y, wa1[4 * i + 1], d1);
          d2 = fmaf(ta.z, wa1[4 * i + 2], d2);
          d3 = fmaf(ta.w, wa1[4 * i + 3], d3);
          f0 = fmaf(tb.x, wa2[4 * i + 0], f0);
          f1 = fmaf(tb.y, wa2[4 * i + 1], f1);
          f2 = fmaf(tb.z, wa2[4 * i + 2], f2);
          f3 = fmaf(tb.w, wa2[4 * i + 3], f3);
        }
        pm0[tid] = (c0 + c1) + (c2 + c3);
        pm1[tid] = (d0 + d1) + (d2 + d3);
        pm2[tid] = (f0 + f1) + (f2 + f3);
        __syncthreads();                           // C: pm ready

        // ---- waves 0..4: reduce c_t, a_t, b_{t+2}; wave 0: j=4 publish
        if (q < NS) {
          float c = 0.f, a = 0.f, bb = 0.f;
#pragma unroll
          for (int s = 0; s < 8; ++s) {
            c  += pm0[s * 64 + ln];
            a  += pm1[s * 64 + ln];
            bb += pm2[s * 64 + ln];
          }
          aA[p] = a;                               // A row t -> slot t%5
          cC[p] = c;                               // c row t -> slot t%5
          if (q == 0 && pub) {
            float x = a + btB + c;                 // row t, bt = row t+1
            float e = __expf(2.0f * x);
            float s4 = (1.0f - 2.0f / (e + 1.0f)) * v_col;
            s4 = wave_sum64(s4);                   // lane 63 = total
            if (ln == 63)
              __hip_atomic_store(&eb[(size_t)((t + 1) & 1) * 64 + 32 + g],
                  (unsigned long long)__float_as_uint(s4) |
                      ((unsigned long long)(t + 2) << 32),
                  __ATOMIC_RELAXED, __HIP_MEMORY_SCOPE_AGENT);
            s4_prev = __shfl(s4, 63, 64);          // off-critical broadcast
          }
          btB = bb;                                // B2 row t+2 for step t+1
        }
        h_cur = h_n1;
        h_n1 = h_n2;
      }
    }
  }
}

extern "C" void kernel_launch(void* const* d_in, const int* in_sizes, int n_in,
                              void* d_out, int out_size, void* d_ws, size_t ws_size,
                              hipStream_t stream) {
  const float* H  = (const float*)d_in[0];
  const float* v  = (const float*)d_in[1];
  const float* W1 = (const float*)d_in[2];
  const float* W2 = (const float*)d_in[3];
  const float* W3 = (const float*)d_in[4];
  float* out = (float*)d_out;

  if (ws_size < WS_NEED) return;

  unsigned long long* exch = (unsigned long long*)d_ws;

  (void)hipMemsetAsync(exch, 0, EXCH_BYTES, stream);
  hipLaunchKernelGGL(th_fused, dim3(BB * 8), dim3(512), 0, stream,
                     H, v, W1, W2, W3, out, exch);
}